// Round 19
// baseline (165.213 us; speedup 1.0000x reference)
//
#include <hip/hip_runtime.h>
#include <hip/hip_fp16.h>

// RNNT Joint: logits[b,t,u,c] = relu(f[b,t,:] + g[b,u,:]) . out_w[c,:] + out_b[c]
// f = enc_out @ enc_w^T + enc_b    [8,512,320]
// g = pred_out @ pred_w^T + pred_b [8,128,320]
// Sizes: B=8 T=512 U=128 E=768 P=320 H=320 C=34

typedef _Float16 f16x8 __attribute__((ext_vector_type(8)));
typedef _Float16 f16x4 __attribute__((ext_vector_type(4)));
typedef __fp16   fp16x2 __attribute__((ext_vector_type(2)));
typedef float    f32x4 __attribute__((ext_vector_type(4)));
typedef int      i32x4 __attribute__((ext_vector_type(4)));

#define B_ 8
#define T_ 512
#define U_ 128
#define H_ 320
#define C_ 34

__device__ inline f16x8 pack8(f32x4 a, f32x4 b) {
    union { fp16x2 h[4]; f16x8 v; } u;
    u.h[0] = __builtin_amdgcn_cvt_pkrtz(a[0], a[1]);
    u.h[1] = __builtin_amdgcn_cvt_pkrtz(a[2], a[3]);
    u.h[2] = __builtin_amdgcn_cvt_pkrtz(b[0], b[1]);
    u.h[3] = __builtin_amdgcn_cvt_pkrtz(b[2], b[3]);
    return u.v;
}

__device__ inline f16x4 pack4(f32x4 a) {
    union { fp16x2 h[2]; f16x4 v; } u;
    u.h[0] = __builtin_amdgcn_cvt_pkrtz(a[0], a[1]);
    u.h[1] = __builtin_amdgcn_cvt_pkrtz(a[2], a[3]);
    return u.v;
}

// ---------------------------------------------------------------------------
// Fused projection GEMMs (proven R7): Out[M][320] = A[M][K]*W[320][K]^T + bias.
// ---------------------------------------------------------------------------
__global__ __launch_bounds__(512, 4)
void proj_fused(const float* __restrict__ enc_out, const float* __restrict__ enc_w,
                const float* __restrict__ enc_b, const float* __restrict__ pred_out,
                const float* __restrict__ pred_w, const float* __restrict__ pred_b,
                _Float16* __restrict__ F, _Float16* __restrict__ G) {
    __shared__ _Float16 As[2][64 * 40];
    __shared__ _Float16 Ws[2][64 * 40];

    int blk = blockIdx.x;
    const float *A, *W, *bias;
    _Float16* Out;
    int K, mt, nt;
    if (blk < 320) {
        A = enc_out; W = enc_w; bias = enc_b; Out = F; K = 768;
        mt = blk & 63; nt = blk >> 6;
    } else {
        blk -= 320;
        A = pred_out; W = pred_w; bias = pred_b; Out = G; K = 320;
        mt = blk & 15; nt = blk >> 4;
    }
    const int bm = mt * 64;
    const int bn = nt * 64;

    const int tid = threadIdx.x;
    const int l   = tid & 63;
    const int w   = tid >> 6;          // 0..7
    const int wm  = (w >> 2) * 32;     // 0,32
    const int wn  = (w & 3) * 16;      // 0,16,32,48
    const int q   = l >> 4;            // 0..3 (k-slice group)
    const int r16 = l & 15;

    const int srow = tid >> 3;         // 0..63
    const int scol = (tid & 7) * 4;    // float col 0,4,...,28

    f32x4 acc[2] = {};

    const float* arow = A + (size_t)(bm + srow) * K + scol;
    const float* wrow = W + (size_t)(bn + srow) * K + scol;

    // 2-deep prologue: K-steps 0 and 32 in flight
    f32x4 aA = *(const f32x4*)(arow);
    f32x4 wA = *(const f32x4*)(wrow);
    f32x4 aB = *(const f32x4*)(arow + 32);
    f32x4 wB = *(const f32x4*)(wrow + 32);

    for (int k0 = 0; k0 < K; k0 += 64) {
        // ---- phase A (buffer 0, K-step k0) ----
        *(f16x4*)&As[0][srow * 40 + scol] = pack4(aA);
        *(f16x4*)&Ws[0][srow * 40 + scol] = pack4(wA);
        if (k0 + 64 < K) {
            aA = *(const f32x4*)(arow + k0 + 64);
            wA = *(const f32x4*)(wrow + k0 + 64);
        }
        __syncthreads();
        {
            f16x8 af0 = *(const f16x8*)&As[0][(wm + r16) * 40 + q * 8];
            f16x8 af1 = *(const f16x8*)&As[0][(wm + 16 + r16) * 40 + q * 8];
            f16x8 bf  = *(const f16x8*)&Ws[0][(wn + r16) * 40 + q * 8];
            acc[0] = __builtin_amdgcn_mfma_f32_16x16x32_f16(af0, bf, acc[0], 0, 0, 0);
            acc[1] = __builtin_amdgcn_mfma_f32_16x16x32_f16(af1, bf, acc[1], 0, 0, 0);
        }
        // ---- phase B (buffer 1, K-step k0+32) ----
        *(f16x4*)&As[1][srow * 40 + scol] = pack4(aB);
        *(f16x4*)&Ws[1][srow * 40 + scol] = pack4(wB);
        if (k0 + 96 < K) {
            aB = *(const f32x4*)(arow + k0 + 96);
            wB = *(const f32x4*)(wrow + k0 + 96);
        }
        __syncthreads();
        {
            f16x8 af0 = *(const f16x8*)&As[1][(wm + r16) * 40 + q * 8];
            f16x8 af1 = *(const f16x8*)&As[1][(wm + 16 + r16) * 40 + q * 8];
            f16x8 bf  = *(const f16x8*)&Ws[1][(wn + r16) * 40 + q * 8];
            acc[0] = __builtin_amdgcn_mfma_f32_16x16x32_f16(af0, bf, acc[0], 0, 0, 0);
            acc[1] = __builtin_amdgcn_mfma_f32_16x16x32_f16(af1, bf, acc[1], 0, 0, 0);
        }
    }

    // Epilogue: C/D layout col = l&15 (n), row = (l>>4)*4 + rr (m)  [m89]
    {
        int col  = bn + wn + r16;
        float bv = bias[col];
#pragma unroll
        for (int mrep = 0; mrep < 2; ++mrep) {
#pragma unroll
            for (int rr = 0; rr < 4; ++rr) {
                int row = bm + wm + mrep * 16 + q * 4 + rr;
                Out[(size_t)row * H_ + col] = (_Float16)(acc[mrep][rr] + bv);
            }
        }
    }
}

// ---------------------------------------------------------------------------
// Joint kernel v13: 512-thread blocks — 8 waves SHARE one ow/F staging.
// Per-CU: 2 blocks x 8 waves = 4 waves/SIMD (2x R17's TLP) at IDENTICAL
// concurrent L2 read-set (512 blocks x same bytes) -> no R13/R15 thrash.
// LDS: ow 34 rows (21760) + flds (20480) + 8 slabs (17408) = 59648 <= 64K.
// Zero rows 34..47 of padded out_w become a r16<2 predicate on bfr[2].
// NT full-line slab dumps; x2-unrolled compute; no VGPR pin (keeps <=128
// for __launch_bounds__(512,4)).
// ---------------------------------------------------------------------------
__global__ __launch_bounds__(512, 4)
void joint_kernel(const _Float16* __restrict__ F, const _Float16* __restrict__ G,
                  const float* __restrict__ out_w, const float* __restrict__ out_b,
                  float* __restrict__ out) {
    __shared__ _Float16 owlds[34 * 320];  // 21760 B; row stride 640 B, XOR-swizzled
    __shared__ _Float16 flds[32 * 320];   // 20480 B; linear
    __shared__ float    olds[8][544];     // 17408 B; per-wave 2176 B output slab

    const int tid = threadIdx.x;
    const int l   = tid & 63;
    const int w   = tid >> 6;    // 0..7
    const int q   = l >> 4;      // 0..3
    const int r16 = l & 15;
    const int tc  = blockIdx.x;  // 0..15 (t-chunk of 32)
    const int ut  = blockIdx.y;  // 0..7 (u-tile of 16)
    const int b   = blockIdx.z;  // 0..7
    const int u0  = ut * 16;

    char* ow = (char*)owlds;

    // stage out_w [34][320] fp32 -> fp16 swizzled LDS [34][320]
    for (int i = tid; i < 34 * 40; i += 512) {   // 1360 chunks of 8 f16
        int n  = i / 40;
        int c8 = (i - n * 40) * 8;               // f16 column
        f32x4 x0 = *(const f32x4*)(out_w + n * H_ + c8);
        f32x4 x1 = *(const f32x4*)(out_w + n * H_ + c8 + 4);
        *(f16x8*)(ow + n * 640 + ((c8 * 2) ^ ((n & 7) << 4))) = pack8(x0, x1);
    }

    // stage F chunk [32][320] f16 -> LDS, fully coalesced (1280 x 16B)
    {
        const _Float16* fsrc = F + ((size_t)b * T_ + tc * 32) * H_;
        for (int i = tid; i < 1280; i += 512)
            *(i32x4*)&flds[i * 8] = *(const i32x4*)(fsrc + i * 8);
    }

    // g fragments: per-lane row u0+r16, loop-invariant over t (A-operand m=u)
    f16x8 gfr[10];
    {
        const _Float16* grow = G + ((size_t)b * U_ + u0 + r16) * H_;
#pragma unroll
        for (int s = 0; s < 10; ++s)
            gfr[s] = *(const f16x8*)(grow + s * 32 + q * 8);
    }

    float ob[3];
#pragma unroll
    for (int nt = 0; nt < 3; ++nt) {
        int n = nt * 16 + r16;
        ob[nt] = (n < C_) ? out_b[n] : 0.f;
    }

    __syncthreads();

    // B-fragments (n=class) from swizzled LDS (conflict-free b128).
    // nt=2: only classes 32,33 exist -> predicate instead of zero-padded rows.
    f16x8 bfr[3][10];
#pragma unroll
    for (int nt = 0; nt < 2; ++nt) {
        int n = nt * 16 + r16;
#pragma unroll
        for (int s = 0; s < 10; ++s)
            bfr[nt][s] = *(const f16x8*)(ow + n * 640 + ((s * 64 + q * 16) ^ ((n & 7) << 4)));
    }
#pragma unroll
    for (int s = 0; s < 10; ++s) {
        f16x8 v = {};
        if (r16 < 2) {
            int n = 32 + r16;
            v = *(const f16x8*)(ow + n * 640 + ((s * 64 + q * 16) ^ ((n & 7) << 4)));
        }
        bfr[2][s] = v;
    }

    float* slab = &olds[w][0];
    const f32x4* src = (const f32x4*)slab;
    const int tloc0 = w * 4;             // each wave owns 4 t-rows

#pragma unroll
    for (int it = 0; it < 2; ++it) {
        const int tl0 = tloc0 + it * 2;
        const _Float16* fr0 = &flds[tl0 * 320];
        const _Float16* fr1 = &flds[(tl0 + 1) * 320];

        f32x4 a00 = {}, a01 = {}, a02 = {};
        f32x4 a10 = {}, a11 = {}, a12 = {};
        __builtin_amdgcn_s_setprio(1);
#pragma unroll
        for (int s = 0; s < 10; ++s) {
            const f16x8 fz = {};
            f16x8 fv0 = *(const f16x8*)(fr0 + s * 32 + q * 8);
            f16x8 fv1 = *(const f16x8*)(fr1 + s * 32 + q * 8);
            f16x8 jv0 = __builtin_elementwise_max(fv0 + gfr[s], fz);
            f16x8 jv1 = __builtin_elementwise_max(fv1 + gfr[s], fz);
            a00 = __builtin_amdgcn_mfma_f32_16x16x32_f16(jv0, bfr[0][s], a00, 0, 0, 0);
            a10 = __builtin_amdgcn_mfma_f32_16x16x32_f16(jv1, bfr[0][s], a10, 0, 0, 0);
            a01 = __builtin_amdgcn_mfma_f32_16x16x32_f16(jv0, bfr[1][s], a01, 0, 0, 0);
            a11 = __builtin_amdgcn_mfma_f32_16x16x32_f16(jv1, bfr[1][s], a11, 0, 0, 0);
            a02 = __builtin_amdgcn_mfma_f32_16x16x32_f16(jv0, bfr[2][s], a02, 0, 0, 0);
            a12 = __builtin_amdgcn_mfma_f32_16x16x32_f16(jv1, bfr[2][s], a12, 0, 0, 0);
        }
        __builtin_amdgcn_s_setprio(0);

        const int t0 = tc * 32 + tl0;
        float* ob0 = out + (((size_t)b * T_ + t0) * U_ + u0) * C_;  // 64B-aligned
        float* ob1 = ob0 + (size_t)U_ * C_;

        // ---- t0: scatter slab, dump NT full-line ----
#pragma unroll
        for (int rr = 0; rr < 4; ++rr) {
            const int m = q * 4 + rr;
            slab[m * 34 + r16]      = a00[rr] + ob[0];
            slab[m * 34 + 16 + r16] = a01[rr] + ob[1];
            if (r16 < 2)
                slab[m * 34 + 32 + r16] = a02[rr] + ob[2];
        }
        {
            f32x4 v0 = src[l];
            f32x4 v1 = src[64 + l];
            __builtin_nontemporal_store(v0, (f32x4*)(ob0 + l * 4));
            __builtin_nontemporal_store(v1, (f32x4*)(ob0 + 256 + l * 4));
            if (l < 8) {
                f32x4 v2 = src[128 + l];
                __builtin_nontemporal_store(v2, (f32x4*)(ob0 + 512 + l * 4));
            }
        }

        // ---- t1: reuse slab (same-wave LDS ops are in order), dump NT ----
#pragma unroll
        for (int rr = 0; rr < 4; ++rr) {
            const int m = q * 4 + rr;
            slab[m * 34 + r16]      = a10[rr] + ob[0];
            slab[m * 34 + 16 + r16] = a11[rr] + ob[1];
            if (r16 < 2)
                slab[m * 34 + 32 + r16] = a12[rr] + ob[2];
        }
        {
            f32x4 v0 = src[l];
            f32x4 v1 = src[64 + l];
            __builtin_nontemporal_store(v0, (f32x4*)(ob1 + l * 4));
            __builtin_nontemporal_store(v1, (f32x4*)(ob1 + 256 + l * 4));
            if (l < 8) {
                f32x4 v2 = src[128 + l];
                __builtin_nontemporal_store(v2, (f32x4*)(ob1 + 512 + l * 4));
            }
        }
    }
}

// ---------------------------------------------------------------------------
extern "C" void kernel_launch(void* const* d_in, const int* in_sizes, int n_in,
                              void* d_out, int out_size, void* d_ws, size_t ws_size,
                              hipStream_t stream) {
    const float* enc_out  = (const float*)d_in[0];
    const float* pred_out = (const float*)d_in[1];
    const float* enc_w    = (const float*)d_in[2];
    const float* enc_b    = (const float*)d_in[3];
    const float* pred_w   = (const float*)d_in[4];
    const float* pred_b   = (const float*)d_in[5];
    const float* out_w    = (const float*)d_in[6];
    const float* out_b    = (const float*)d_in[7];
    float* out = (float*)d_out;

    char* ws = (char*)d_ws;
    _Float16* F = (_Float16*)ws;                            // 4096*320 fp16
    _Float16* G = (_Float16*)(ws + (size_t)4096 * 320 * 2); // 1024*320 fp16

    proj_fused<<<400, 512, 0, stream>>>(enc_out, enc_w, enc_b,
                                        pred_out, pred_w, pred_b, F, G);
    joint_kernel<<<dim3(16, 8, 8), 512, 0, stream>>>(F, G, out_w, out_b, out);
}

// Round 20
// 41.630 us; speedup vs baseline: 3.9686x; 3.9686x over previous
//
#include <hip/hip_runtime.h>
#include <hip/hip_fp16.h>

// RNNT Joint: logits[b,t,u,c] = relu(f[b,t,:] + g[b,u,:]) . out_w[c,:] + out_b[c]
// f = enc_out @ enc_w^T + enc_b    [8,512,320]
// g = pred_out @ pred_w^T + pred_b [8,128,320]
// Sizes: B=8 T=512 U=128 E=768 P=320 H=320 C=34

typedef _Float16 f16x8 __attribute__((ext_vector_type(8)));
typedef _Float16 f16x4 __attribute__((ext_vector_type(4)));
typedef __fp16   fp16x2 __attribute__((ext_vector_type(2)));
typedef float    f32x4 __attribute__((ext_vector_type(4)));
typedef int      i32x4 __attribute__((ext_vector_type(4)));

#define B_ 8
#define T_ 512
#define U_ 128
#define H_ 320
#define C_ 34

__device__ inline f16x8 pack8(f32x4 a, f32x4 b) {
    union { fp16x2 h[4]; f16x8 v; } u;
    u.h[0] = __builtin_amdgcn_cvt_pkrtz(a[0], a[1]);
    u.h[1] = __builtin_amdgcn_cvt_pkrtz(a[2], a[3]);
    u.h[2] = __builtin_amdgcn_cvt_pkrtz(b[0], b[1]);
    u.h[3] = __builtin_amdgcn_cvt_pkrtz(b[2], b[3]);
    return u.v;
}

__device__ inline f16x4 pack4(f32x4 a) {
    union { fp16x2 h[2]; f16x4 v; } u;
    u.h[0] = __builtin_amdgcn_cvt_pkrtz(a[0], a[1]);
    u.h[1] = __builtin_amdgcn_cvt_pkrtz(a[2], a[3]);
    return u.v;
}

// ---------------------------------------------------------------------------
// Fused projection GEMMs (proven R7): Out[M][320] = A[M][K]*W[320][K]^T + bias.
// ---------------------------------------------------------------------------
__global__ __launch_bounds__(512, 4)
void proj_fused(const float* __restrict__ enc_out, const float* __restrict__ enc_w,
                const float* __restrict__ enc_b, const float* __restrict__ pred_out,
                const float* __restrict__ pred_w, const float* __restrict__ pred_b,
                _Float16* __restrict__ F, _Float16* __restrict__ G) {
    __shared__ _Float16 As[2][64 * 40];
    __shared__ _Float16 Ws[2][64 * 40];

    int blk = blockIdx.x;
    const float *A, *W, *bias;
    _Float16* Out;
    int K, mt, nt;
    if (blk < 320) {
        A = enc_out; W = enc_w; bias = enc_b; Out = F; K = 768;
        mt = blk & 63; nt = blk >> 6;
    } else {
        blk -= 320;
        A = pred_out; W = pred_w; bias = pred_b; Out = G; K = 320;
        mt = blk & 15; nt = blk >> 4;
    }
    const int bm = mt * 64;
    const int bn = nt * 64;

    const int tid = threadIdx.x;
    const int l   = tid & 63;
    const int w   = tid >> 6;          // 0..7
    const int wm  = (w >> 2) * 32;     // 0,32
    const int wn  = (w & 3) * 16;      // 0,16,32,48
    const int q   = l >> 4;            // 0..3 (k-slice group)
    const int r16 = l & 15;

    const int srow = tid >> 3;         // 0..63
    const int scol = (tid & 7) * 4;    // float col 0,4,...,28

    f32x4 acc[2] = {};

    const float* arow = A + (size_t)(bm + srow) * K + scol;
    const float* wrow = W + (size_t)(bn + srow) * K + scol;

    // 2-deep prologue: K-steps 0 and 32 in flight
    f32x4 aA = *(const f32x4*)(arow);
    f32x4 wA = *(const f32x4*)(wrow);
    f32x4 aB = *(const f32x4*)(arow + 32);
    f32x4 wB = *(const f32x4*)(wrow + 32);

    for (int k0 = 0; k0 < K; k0 += 64) {
        // ---- phase A (buffer 0, K-step k0) ----
        *(f16x4*)&As[0][srow * 40 + scol] = pack4(aA);
        *(f16x4*)&Ws[0][srow * 40 + scol] = pack4(wA);
        if (k0 + 64 < K) {
            aA = *(const f32x4*)(arow + k0 + 64);
            wA = *(const f32x4*)(wrow + k0 + 64);
        }
        __syncthreads();
        {
            f16x8 af0 = *(const f16x8*)&As[0][(wm + r16) * 40 + q * 8];
            f16x8 af1 = *(const f16x8*)&As[0][(wm + 16 + r16) * 40 + q * 8];
            f16x8 bf  = *(const f16x8*)&Ws[0][(wn + r16) * 40 + q * 8];
            acc[0] = __builtin_amdgcn_mfma_f32_16x16x32_f16(af0, bf, acc[0], 0, 0, 0);
            acc[1] = __builtin_amdgcn_mfma_f32_16x16x32_f16(af1, bf, acc[1], 0, 0, 0);
        }
        // ---- phase B (buffer 1, K-step k0+32) ----
        *(f16x4*)&As[1][srow * 40 + scol] = pack4(aB);
        *(f16x4*)&Ws[1][srow * 40 + scol] = pack4(wB);
        if (k0 + 96 < K) {
            aB = *(const f32x4*)(arow + k0 + 96);
            wB = *(const f32x4*)(wrow + k0 + 96);
        }
        __syncthreads();
        {
            f16x8 af0 = *(const f16x8*)&As[1][(wm + r16) * 40 + q * 8];
            f16x8 af1 = *(const f16x8*)&As[1][(wm + 16 + r16) * 40 + q * 8];
            f16x8 bf  = *(const f16x8*)&Ws[1][(wn + r16) * 40 + q * 8];
            acc[0] = __builtin_amdgcn_mfma_f32_16x16x32_f16(af0, bf, acc[0], 0, 0, 0);
            acc[1] = __builtin_amdgcn_mfma_f32_16x16x32_f16(af1, bf, acc[1], 0, 0, 0);
        }
    }

    // Epilogue: C/D layout col = l&15 (n), row = (l>>4)*4 + rr (m)  [m89]
    {
        int col  = bn + wn + r16;
        float bv = bias[col];
#pragma unroll
        for (int mrep = 0; mrep < 2; ++mrep) {
#pragma unroll
            for (int rr = 0; rr < 4; ++rr) {
                int row = bm + wm + mrep * 16 + q * 4 + rr;
                Out[(size_t)row * H_ + col] = (_Float16)(acc[mrep][rr] + bv);
            }
        }
    }
}

// ---------------------------------------------------------------------------
// Joint kernel v14: bfr FORCED register-resident via slab overlay, at a VGPR
// cap that fits. Overlaying the slabs on the dead out_w staging region makes
// LDS re-reads of bfr impossible -> compiler must keep 120 VGPRs of bfr live.
// __launch_bounds__(256,2) = 256-VGPR cap (bfr 120 + gfr 40 + acc 24 + temps
// ~= 200 fits -> NO spill; R13/R15/R19 failed because their caps were 128-170).
// LDS: ow 30720 + flds 20480 = 51200 B; slabs overlaid; 2 blocks/CU.
// t-loop per iter: 20 F ds_reads + 60 MFMA (all operands in regs) + slab
// scatter + NT full-line dumps. 30 bfr LDS re-reads/iter ELIMINATED.
// ---------------------------------------------------------------------------
__global__ __launch_bounds__(256, 2)
void joint_kernel(const _Float16* __restrict__ F, const _Float16* __restrict__ G,
                  const float* __restrict__ out_w, const float* __restrict__ out_b,
                  float* __restrict__ out) {
    __shared__ _Float16 regA[48 * 320];   // 30720 B: ow staging, then output slabs
    __shared__ _Float16 flds[32 * 320];   // 20480 B: F chunk

    const int tid = threadIdx.x;
    const int l   = tid & 63;
    const int w   = tid >> 6;
    const int q   = l >> 4;    // 0..3
    const int r16 = l & 15;
    const int tc  = blockIdx.x;  // 0..15 (t-chunk of 32)
    const int ut  = blockIdx.y;  // 0..7 (u-tile of 16)
    const int b   = blockIdx.z;  // 0..7
    const int u0  = ut * 16;

    char* ow = (char*)regA;

    // stage out_w [34][320] fp32 -> fp16 swizzled LDS [48][320] (rows 34..47 = 0)
    for (int i = tid; i < 48 * 40; i += 256) {   // 1920 chunks of 8 f16
        int n  = i / 40;
        int c8 = (i - n * 40) * 8;               // f16 column
        f16x8 v = {};
        if (n < C_) {
            f32x4 x0 = *(const f32x4*)(out_w + n * H_ + c8);
            f32x4 x1 = *(const f32x4*)(out_w + n * H_ + c8 + 4);
            v = pack8(x0, x1);
        }
        *(f16x8*)(ow + n * 640 + ((c8 * 2) ^ ((n & 7) << 4))) = v;
    }

    // stage F chunk [32][320] f16 -> LDS, fully coalesced (1280 x 16B)
    {
        const _Float16* fsrc = F + ((size_t)b * T_ + tc * 32) * H_;
        for (int i = tid; i < 1280; i += 256)
            *(i32x4*)&flds[i * 8] = *(const i32x4*)(fsrc + i * 8);
    }

    // g fragments: per-lane row u0+r16, loop-invariant over t (A-operand m=u)
    f16x8 gfr[10];
    {
        const _Float16* grow = G + ((size_t)b * U_ + u0 + r16) * H_;
#pragma unroll
        for (int s = 0; s < 10; ++s)
            gfr[s] = *(const f16x8*)(grow + s * 32 + q * 8);
    }

    float ob[3];
#pragma unroll
    for (int nt = 0; nt < 3; ++nt) {
        int n = nt * 16 + r16;
        ob[nt] = (n < C_) ? out_b[n] : 0.f;
    }

    __syncthreads();  // ow staging complete

    // B-fragments (n=class) from swizzled LDS (conflict-free b128)
    f16x8 bfr[3][10];
#pragma unroll
    for (int nt = 0; nt < 3; ++nt) {
        int n = nt * 16 + r16;
#pragma unroll
        for (int s = 0; s < 10; ++s)
            bfr[nt][s] = *(const f16x8*)(ow + n * 640 + ((s * 64 + q * 16) ^ ((n & 7) << 4)));
    }

    __syncthreads();  // all waves done reading ow -> regA becomes the slabs
                      // (overlay kills any possibility of bfr LDS re-reads)

    float* slab = (float*)regA + w * 544;   // per-wave 2176 B slab (overlay)
    const f32x4* src = (const f32x4*)slab;
    const int tloc0 = w * 8;                // local t row within chunk

#pragma unroll
    for (int it = 0; it < 4; ++it) {
        const int tl0 = tloc0 + it * 2;
        const _Float16* fr0 = &flds[tl0 * 320];
        const _Float16* fr1 = &flds[(tl0 + 1) * 320];

        f32x4 a00 = {}, a01 = {}, a02 = {};
        f32x4 a10 = {}, a11 = {}, a12 = {};
        __builtin_amdgcn_s_setprio(1);
#pragma unroll
        for (int s = 0; s < 10; ++s) {
            const f16x8 fz = {};
            f16x8 fv0 = *(const f16x8*)(fr0 + s * 32 + q * 8);
            f16x8 fv1 = *(const f16x8*)(fr1 + s * 32 + q * 8);
            f16x8 jv0 = __builtin_elementwise_max(fv0 + gfr[s], fz);
            f16x8 jv1 = __builtin_elementwise_max(fv1 + gfr[s], fz);
            a00 = __builtin_amdgcn_mfma_f32_16x16x32_f16(jv0, bfr[0][s], a00, 0, 0, 0);
            a10 = __builtin_amdgcn_mfma_f32_16x16x32_f16(jv1, bfr[0][s], a10, 0, 0, 0);
            a01 = __builtin_amdgcn_mfma_f32_16x16x32_f16(jv0, bfr[1][s], a01, 0, 0, 0);
            a11 = __builtin_amdgcn_mfma_f32_16x16x32_f16(jv1, bfr[1][s], a11, 0, 0, 0);
            a02 = __builtin_amdgcn_mfma_f32_16x16x32_f16(jv0, bfr[2][s], a02, 0, 0, 0);
            a12 = __builtin_amdgcn_mfma_f32_16x16x32_f16(jv1, bfr[2][s], a12, 0, 0, 0);
        }
        __builtin_amdgcn_s_setprio(0);

        const int t0 = tc * 32 + tl0;
        float* ob0 = out + (((size_t)b * T_ + t0) * U_ + u0) * C_;  // 64B-aligned
        float* ob1 = ob0 + (size_t)U_ * C_;

        // ---- t0: scatter slab, dump NT full-line ----
#pragma unroll
        for (int rr = 0; rr < 4; ++rr) {
            const int m = q * 4 + rr;
            slab[m * 34 + r16]      = a00[rr] + ob[0];
            slab[m * 34 + 16 + r16] = a01[rr] + ob[1];
            if (r16 < 2)
                slab[m * 34 + 32 + r16] = a02[rr] + ob[2];
        }
        {
            f32x4 v0 = src[l];
            f32x4 v1 = src[64 + l];
            __builtin_nontemporal_store(v0, (f32x4*)(ob0 + l * 4));
            __builtin_nontemporal_store(v1, (f32x4*)(ob0 + 256 + l * 4));
            if (l < 8) {
                f32x4 v2 = src[128 + l];
                __builtin_nontemporal_store(v2, (f32x4*)(ob0 + 512 + l * 4));
            }
        }

        // ---- t1: reuse slab (same-wave LDS ops retire in order), dump NT ----
#pragma unroll
        for (int rr = 0; rr < 4; ++rr) {
            const int m = q * 4 + rr;
            slab[m * 34 + r16]      = a10[rr] + ob[0];
            slab[m * 34 + 16 + r16] = a11[rr] + ob[1];
            if (r16 < 2)
                slab[m * 34 + 32 + r16] = a12[rr] + ob[2];
        }
        {
            f32x4 v0 = src[l];
            f32x4 v1 = src[64 + l];
            __builtin_nontemporal_store(v0, (f32x4*)(ob1 + l * 4));
            __builtin_nontemporal_store(v1, (f32x4*)(ob1 + 256 + l * 4));
            if (l < 8) {
                f32x4 v2 = src[128 + l];
                __builtin_nontemporal_store(v2, (f32x4*)(ob1 + 512 + l * 4));
            }
        }
    }
}

// ---------------------------------------------------------------------------
extern "C" void kernel_launch(void* const* d_in, const int* in_sizes, int n_in,
                              void* d_out, int out_size, void* d_ws, size_t ws_size,
                              hipStream_t stream) {
    const float* enc_out  = (const float*)d_in[0];
    const float* pred_out = (const float*)d_in[1];
    const float* enc_w    = (const float*)d_in[2];
    const float* enc_b    = (const float*)d_in[3];
    const float* pred_w   = (const float*)d_in[4];
    const float* pred_b   = (const float*)d_in[5];
    const float* out_w    = (const float*)d_in[6];
    const float* out_b    = (const float*)d_in[7];
    float* out = (float*)d_out;

    char* ws = (char*)d_ws;
    _Float16* F = (_Float16*)ws;                            // 4096*320 fp16
    _Float16* G = (_Float16*)(ws + (size_t)4096 * 320 * 2); // 1024*320 fp16

    proj_fused<<<400, 512, 0, stream>>>(enc_out, enc_w, enc_b,
                                        pred_out, pred_w, pred_b, F, G);
    joint_kernel<<<dim3(16, 8, 8), 256, 0, stream>>>(F, G, out_w, out_b, out);
}